// Round 6
// baseline (398.890 us; speedup 1.0000x reference)
//
#include <hip/hip_runtime.h>
#include <hip/hip_bf16.h>

// x (B=256, R=1024, C=1024) fp32; rows/cols: 64 int32 indices each.
// out = x, except at (b, rows[i], cols[j]) apply mute_msb:
//   if biased exponent E in [127,255) (|x|>=1, finite): set exponent to 126
//   (x -> signed mantissa in [0.5,1)); else identity.
//
// Single fused streaming kernel at minimal traffic (2.15 GB):
//  - each block builds the row/col bitmasks in LDS from the 512 B index
//    arrays (parallel across blocks; removes the serialized pre-kernel)
//  - row-per-block decomposition, one float4 per lane per row
//  - UNROLL=8 software pipeline: 8 nontemporal loads in flight while the
//    previous 8 rows mute+store (HBM latency ~900 cyc wants deep MLP)

#define RR 1024
#define CC 1024
#define UNROLL 8

typedef float f4 __attribute__((ext_vector_type(4)));

__device__ __forceinline__ void mute4(f4& v, unsigned m) {
#pragma unroll
    for (int k = 0; k < 4; ++k) {
        if ((m >> k) & 1u) {
            unsigned u = __float_as_uint(v[k]);
            unsigned E = (u >> 23) & 0xffu;
            if (E >= 127u && E < 255u)
                v[k] = __uint_as_float((u & 0x807fffffu) | (126u << 23));
        }
    }
}

__global__ void __launch_bounds__(256)
copy_mute_kernel(const f4* __restrict__ x,
                 f4* __restrict__ out,
                 const int* __restrict__ rows,
                 const int* __restrict__ cols,
                 int nr, int nc, int nrows) {          // nrows = B * R
    // Per-block mask build: smask[0..31] row bits, smask[32..63] col bits.
    __shared__ unsigned smask[64];
    int tid = threadIdx.x;
    if (tid < 64) smask[tid] = 0u;
    __syncthreads();
    if (tid < nr) {
        int r = rows[tid];
        atomicOr(&smask[r >> 5], 1u << (r & 31));
    } else if (tid >= 64 && tid < 64 + nc) {
        int c = cols[tid - 64];
        atomicOr(&smask[32 + (c >> 5)], 1u << (c & 31));
    }
    __syncthreads();

    // This lane always handles columns [tid*4, tid*4+4): nibble is invariant.
    unsigned colword = smask[32 + (tid >> 3)];
    unsigned colnib = (colword >> ((tid & 7) * 4)) & 0xFu;

    int rowstride = gridDim.x * UNROLL;               // rows per sweep
    long long qstride = (long long)rowstride * 256;   // f4 units

    int row = blockIdx.x * UNROLL;
    if (row >= nrows) return;
    long long q = (long long)row * 256 + tid;

    f4 v[UNROLL];
#pragma unroll
    for (int k = 0; k < UNROLL; ++k)
        v[k] = __builtin_nontemporal_load(&x[q + k * 256]);

    for (;;) {
        int nrow = row + rowstride;
        bool more = nrow < nrows;
        long long nq = q + qstride;

        f4 n[UNROLL];
        if (more) {
#pragma unroll
            for (int k = 0; k < UNROLL; ++k)
                n[k] = __builtin_nontemporal_load(&x[nq + k * 256]);
        }

#pragma unroll
        for (int k = 0; k < UNROLL; ++k) {
            int r = (row + k) & (RR - 1);
            unsigned m = ((smask[r >> 5] >> (r & 31)) & 1u) ? colnib : 0u;
            if (m) mute4(v[k], m);
            __builtin_nontemporal_store(v[k], &out[q + k * 256]);
        }

        if (!more) break;
#pragma unroll
        for (int k = 0; k < UNROLL; ++k) v[k] = n[k];
        row = nrow;
        q = nq;
    }
}

extern "C" void kernel_launch(void* const* d_in, const int* in_sizes, int n_in,
                              void* d_out, int out_size, void* d_ws, size_t ws_size,
                              hipStream_t stream) {
    const float* x  = (const float*)d_in[0];
    const int* rows = (const int*)d_in[1];
    const int* cols = (const int*)d_in[2];
    float* out      = (float*)d_out;

    const int nr = in_sizes[1];
    const int nc = in_sizes[2];

    int nrows = in_sizes[0] / CC;   // B * R = 262144
    int block = 256;
    int grid = 4096;
    if (grid * UNROLL > nrows) grid = (nrows + UNROLL - 1) / UNROLL;
    copy_mute_kernel<<<grid, block, 0, stream>>>(
        (const f4*)x, (f4*)out, rows, cols, nr, nc, nrows);
}

// Round 7
// 374.328 us; speedup vs baseline: 1.0656x; 1.0656x over previous
//
#include <hip/hip_runtime.h>
#include <hip/hip_bf16.h>

// x (B=256, R=1024, C=1024) fp32; rows/cols: 64 int32 indices each.
// out = x, except at (b, rows[i], cols[j]) apply mute_msb:
//   if biased exponent E in [127,255) (|x|>=1, finite): set exponent to 126
//   (x -> signed mantissa in [0.5,1)); else identity.
//
// Streaming copy at minimal traffic (2.15 GB), best structure so far (R5)
// minus per-iteration overhead:
//  - ping-pong A/B register buffers (no v=n shift copies)
//  - rowstride = grid*UNROLL multiple of R=1024 -> each block's (row mod R)
//    is loop-invariant -> row-membership bits + mute nibbles hoisted out of
//    the loop; inner loop is a pure nontemporal float4 copy for ~94% of
//    blocks.

#define RR 1024
#define CC 1024
#define UNROLL 4

typedef float f4 __attribute__((ext_vector_type(4)));

__global__ void build_masks_kernel(const int* __restrict__ rows,
                                   const int* __restrict__ cols,
                                   unsigned* __restrict__ masks, // [64]: 0..31 row bits, 32..63 col bits
                                   int nr, int nc) {
    int t = threadIdx.x;
    if (t < 64) masks[t] = 0u;
    __syncthreads();
    if (t < nr) {
        int r = rows[t];
        atomicOr(&masks[r >> 5], 1u << (r & 31));
    }
    if (t < nc) {
        int c = cols[t];
        atomicOr(&masks[32 + (c >> 5)], 1u << (c & 31));
    }
}

__device__ __forceinline__ void mute4(f4& v, unsigned m) {
#pragma unroll
    for (int k = 0; k < 4; ++k) {
        if ((m >> k) & 1u) {
            unsigned u = __float_as_uint(v[k]);
            unsigned E = (u >> 23) & 0xffu;
            if (E >= 127u && E < 255u)
                v[k] = __uint_as_float((u & 0x807fffffu) | (126u << 23));
        }
    }
}

#define LOADV(V, qq)                                                        \
    _Pragma("unroll") for (int k = 0; k < UNROLL; ++k)                      \
        V[k] = __builtin_nontemporal_load(&x[(qq) + k * 256]);

#define PSTOREV(V, qq)                                                      \
    _Pragma("unroll") for (int k = 0; k < UNROLL; ++k) {                    \
        f4 t = V[k];                                                        \
        if (rb[k]) mute4(t, mnib[k]);                                       \
        __builtin_nontemporal_store(t, &out[(qq) + k * 256]);               \
    }

__global__ void __launch_bounds__(256)
copy_mute_kernel(const f4* __restrict__ x,
                 f4* __restrict__ out,
                 const unsigned* __restrict__ masks,
                 int nrows) {                          // nrows = B * R
    __shared__ unsigned rowmask[32];
    int tid = threadIdx.x;
    if (tid < 32) rowmask[tid] = masks[tid];
    __syncthreads();

    // This lane always handles columns [tid*4, tid*4+4): nibble invariant.
    unsigned colword = masks[32 + (tid >> 3)];
    unsigned colnib = (colword >> ((tid & 7) * 4)) & 0xFu;

    int row0 = blockIdx.x * UNROLL;
    if (row0 >= nrows) return;
    int rowstride = gridDim.x * UNROLL;               // host guarantees % RR == 0 (or iters==1)
    long long qstride = (long long)rowstride * 256;

    // Loop-invariant row membership (row mod RR constant across iterations).
    bool rb[UNROLL];
    unsigned mnib[UNROLL];
#pragma unroll
    for (int k = 0; k < UNROLL; ++k) {
        int r = (row0 + k) & (RR - 1);
        rb[k] = ((rowmask[r >> 5] >> (r & 31)) & 1u) != 0u;
        mnib[k] = colnib;
    }

    int iters = (nrows - row0 + rowstride - 1) / rowstride;
    long long q0 = (long long)row0 * 256 + tid;

    f4 A[UNROLL], B[UNROLL];
    LOADV(A, q0)
    long long qprev = q0;
    bool prevA = true;
    for (int t = 1; t < iters; ++t) {
        long long qt = qprev + qstride;
        if (prevA) { LOADV(B, qt) PSTOREV(A, qprev) }
        else       { LOADV(A, qt) PSTOREV(B, qprev) }
        prevA = !prevA;
        qprev = qt;
    }
    if (prevA) { PSTOREV(A, qprev) }
    else       { PSTOREV(B, qprev) }
}

extern "C" void kernel_launch(void* const* d_in, const int* in_sizes, int n_in,
                              void* d_out, int out_size, void* d_ws, size_t ws_size,
                              hipStream_t stream) {
    const float* x  = (const float*)d_in[0];
    const int* rows = (const int*)d_in[1];
    const int* cols = (const int*)d_in[2];
    float* out      = (float*)d_out;
    unsigned* masks = (unsigned*)d_ws;

    const int nr = in_sizes[1];
    const int nc = in_sizes[2];

    build_masks_kernel<<<1, 64, 0, stream>>>(rows, cols, masks, nr, nc);

    int nrows = in_sizes[0] / CC;   // B * R = 262144
    int block = 256;
    int grid = 4096;                // 4096*4 = 16384 rows/sweep, % 1024 == 0
    if (grid * UNROLL > nrows) grid = (nrows + UNROLL - 1) / UNROLL;  // -> iters==1
    copy_mute_kernel<<<grid, block, 0, stream>>>(
        (const f4*)x, (f4*)out, masks, nrows);
}

// Round 8
// 372.092 us; speedup vs baseline: 1.0720x; 1.0060x over previous
//
#include <hip/hip_runtime.h>
#include <hip/hip_bf16.h>

// x (B=256, R=1024, C=1024) fp32; rows/cols: 64 int32 indices each.
// out = x, except at (b, rows[i], cols[j]) apply mute_msb:
//   if biased exponent E in [127,255) (|x|>=1, finite): set exponent to 126
//   (x -> signed mantissa in [0.5,1)); else identity.
//
// Single fused streaming kernel at minimal traffic (2.15 GB):
//  - per-block LDS bitmask build from the 512 B index arrays (parallel,
//    overlapped; removes the serialized pre-kernel launch)   [R8 change]
//  - ping-pong A/B register buffers (no shift copies)        [from R7]
//  - rowstride multiple of R=1024 -> (row mod R) loop-invariant -> row
//    membership + mute nibbles hoisted; inner loop is a pure nontemporal
//    float4 copy for ~94% of blocks.                         [from R7]

#define RR 1024
#define CC 1024
#define UNROLL 4

typedef float f4 __attribute__((ext_vector_type(4)));

__device__ __forceinline__ void mute4(f4& v, unsigned m) {
#pragma unroll
    for (int k = 0; k < 4; ++k) {
        if ((m >> k) & 1u) {
            unsigned u = __float_as_uint(v[k]);
            unsigned E = (u >> 23) & 0xffu;
            if (E >= 127u && E < 255u)
                v[k] = __uint_as_float((u & 0x807fffffu) | (126u << 23));
        }
    }
}

#define LOADV(V, qq)                                                        \
    _Pragma("unroll") for (int k = 0; k < UNROLL; ++k)                      \
        V[k] = __builtin_nontemporal_load(&x[(qq) + k * 256]);

#define PSTOREV(V, qq)                                                      \
    _Pragma("unroll") for (int k = 0; k < UNROLL; ++k) {                    \
        f4 t = V[k];                                                        \
        if (rb[k]) mute4(t, colnib);                                        \
        __builtin_nontemporal_store(t, &out[(qq) + k * 256]);               \
    }

__global__ void __launch_bounds__(256)
copy_mute_kernel(const f4* __restrict__ x,
                 f4* __restrict__ out,
                 const int* __restrict__ rows,
                 const int* __restrict__ cols,
                 int nr, int nc, int nrows) {          // nrows = B * R
    // Per-block mask build: smask[0..31] row bits, smask[32..63] col bits.
    __shared__ unsigned smask[64];
    int tid = threadIdx.x;
    if (tid < 64) smask[tid] = 0u;
    __syncthreads();
    if (tid < nr) {
        int r = rows[tid];
        atomicOr(&smask[r >> 5], 1u << (r & 31));
    } else if (tid >= 64 && tid < 64 + nc) {
        int c = cols[tid - 64];
        atomicOr(&smask[32 + (c >> 5)], 1u << (c & 31));
    }
    __syncthreads();

    // This lane always handles columns [tid*4, tid*4+4): nibble invariant.
    unsigned colword = smask[32 + (tid >> 3)];
    unsigned colnib = (colword >> ((tid & 7) * 4)) & 0xFu;

    int row0 = blockIdx.x * UNROLL;
    if (row0 >= nrows) return;
    int rowstride = gridDim.x * UNROLL;               // host guarantees % RR == 0 (or iters==1)
    long long qstride = (long long)rowstride * 256;

    // Loop-invariant row membership (row mod RR constant across iterations).
    bool rb[UNROLL];
#pragma unroll
    for (int k = 0; k < UNROLL; ++k) {
        int r = (row0 + k) & (RR - 1);
        rb[k] = ((smask[r >> 5] >> (r & 31)) & 1u) != 0u;
    }

    int iters = (nrows - row0 + rowstride - 1) / rowstride;
    long long q0 = (long long)row0 * 256 + tid;

    f4 A[UNROLL], B[UNROLL];
    LOADV(A, q0)
    long long qprev = q0;
    bool prevA = true;
    for (int t = 1; t < iters; ++t) {
        long long qt = qprev + qstride;
        if (prevA) { LOADV(B, qt) PSTOREV(A, qprev) }
        else       { LOADV(A, qt) PSTOREV(B, qprev) }
        prevA = !prevA;
        qprev = qt;
    }
    if (prevA) { PSTOREV(A, qprev) }
    else       { PSTOREV(B, qprev) }
}

extern "C" void kernel_launch(void* const* d_in, const int* in_sizes, int n_in,
                              void* d_out, int out_size, void* d_ws, size_t ws_size,
                              hipStream_t stream) {
    const float* x  = (const float*)d_in[0];
    const int* rows = (const int*)d_in[1];
    const int* cols = (const int*)d_in[2];
    float* out      = (float*)d_out;

    const int nr = in_sizes[1];
    const int nc = in_sizes[2];

    int nrows = in_sizes[0] / CC;   // B * R = 262144
    int block = 256;
    int grid = 4096;                // 4096*4 = 16384 rows/sweep, % 1024 == 0
    if (grid * UNROLL > nrows) grid = (nrows + UNROLL - 1) / UNROLL;  // -> iters==1
    copy_mute_kernel<<<grid, block, 0, stream>>>(
        (const f4*)x, (f4*)out, rows, cols, nr, nc, nrows);
}